// Round 6
// baseline (335.715 us; speedup 1.0000x reference)
//
#include <hip/hip_runtime.h>
#include <hip/hip_fp16.h>
#include <cstddef>

#define Bc   32
#define Nc   512
#define Mc   512
#define DFc  64
#define BIGC 1.0e10f
#define LOG2E_F 1.4426950408889634f
#define LN2_F   0.6931471805599453f
#define SQRT_LOG2E_F 1.2011224087864498f

// Dsk layout: per batch, slot (s, L) at (s*64 + L)*16 bytes, s in [0,1023].
// Slot half r = D[8L + r][s - 8L - r - 1] (scaled log2-domain dist + 127),
// i.e. the 8 cells lane L computes at scan step s (anti-diagonal i+j = s+1).
// Batch stride 1 MB; 32 batches = 32 MB (memset-0 so unwritten slots are finite).
#define BSTRIDE 1048576

typedef unsigned int uint32;
typedef _Float16 f16x8 __attribute__((ext_vector_type(8)));
typedef float    f32x4 __attribute__((ext_vector_type(4)));

__device__ __forceinline__ float dpp_shr1(float oldv, float src) {
    return __int_as_float(__builtin_amdgcn_update_dpp(
        __float_as_int(oldv), __float_as_int(src), 0x138, 0xf, 0xf, false));
}
__device__ __forceinline__ float rl(float v, int lane) {
    return __int_as_float(__builtin_amdgcn_readlane(__float_as_int(v), lane));
}

// Bit-trick softmin, log2 domain, minus 127 (bias pre-folded into Dsk).
// v_cvt_u32_f32 saturates negative inputs to 0 (= exp underflow), so ~1e10
// free-run operands behave identically to exact BIG borders.
__device__ __forceinline__ float softmin3m(float a, float b, float c) {
    float mn = fminf(fminf(a, b), c);
    float mx = fmaxf(fmaxf(a, b), c);
    float md = __builtin_amdgcn_fmed3f(a, b, c);
    uint32 b1 = (uint32)fmaf(mn - mx, 8388608.0f, 1065353216.0f);
    uint32 b2 = (uint32)fmaf(mn - md, 8388608.0f, 1065353216.0f);
    float E = 1.0f + (__int_as_float(b1) + __int_as_float(b2));
    return fmaf((float)__float_as_uint(E), -1.1920929e-7f, mn);
}

// ---------------------------------------------------------------------------
// Kernel 1: MFMA distance computation, chunked. Grid (4 strips, 32 batches),
// 512 threads. Block owns rows [128*strip, +128) and sweeps 4 column-chunks
// of 128, keeping a 7-column halo in P2 so every anti-diagonal slot (which
// spans 8 columns) is completed by exactly one block.
// ---------------------------------------------------------------------------
__global__ __launch_bounds__(512) void dist_kernel(
    const float* __restrict__ X, const float* __restrict__ Y,
    uint32* __restrict__ Dsk)
{
    __shared__ __align__(16) unsigned char SMEM[71872];
    unsigned short* XsH = (unsigned short*)SMEM;             // 16384 B
    unsigned short* YsH = (unsigned short*)(SMEM + 16384);   // 16384 B
    unsigned short* P2h = (unsigned short*)(SMEM + 32768);   // [c_l<=135]*140+row, 38080 B
    float* xx2 = (float*)(SMEM + 70848);                     // 512 B
    float* yy2 = (float*)(SMEM + 71360);                     // 512 B

    const int strip = blockIdx.x;
    const int b     = blockIdx.y;
    const int tid   = threadIdx.x;

    const float* Xg = X + ((size_t)b * Nc + strip * 128) * DFc;

    // ---- stage X strip (once): scaled f16, rotated; f32 row norms ----
#pragma unroll
    for (int it = 0; it < 4; ++it) {
        int e4 = it * 512 + tid;
        int n = e4 >> 4, k4 = (e4 & 15) * 4;
        float4 v = ((const float4*)Xg)[e4];
        float sx = v.x * SQRT_LOG2E_F, sy = v.y * SQRT_LOG2E_F;
        float sz = v.z * SQRT_LOG2E_F, sw = v.w * SQRT_LOG2E_F;
        __half2 h01 = __floats2half2_rn(sx, sy);
        __half2 h23 = __floats2half2_rn(sz, sw);
        int ho = (k4 + 8 * (n & 7)) & 63;
        uint2 u; u.x = *(uint32*)&h01; u.y = *(uint32*)&h23;
        *(uint2*)&XsH[n * 64 + ho] = u;
        float p = sx * sx + sy * sy + sz * sz + sw * sw;
        p += __shfl_xor(p, 1);
        p += __shfl_xor(p, 2);
        p += __shfl_xor(p, 4);
        p += __shfl_xor(p, 8);
        if ((tid & 15) == 0) xx2[n] = p + 127.0f;   // fold the +127 bias
    }
    // ---- stage Y chunk 0 + norms ----
    {
        const float* Yg = Y + ((size_t)b * Mc + 0) * DFc;
#pragma unroll
        for (int it = 0; it < 4; ++it) {
            int e4 = it * 512 + tid;
            int m = e4 >> 4, k4 = (e4 & 15) * 4;
            float4 v = ((const float4*)Yg)[e4];
            float sx = v.x * SQRT_LOG2E_F, sy = v.y * SQRT_LOG2E_F;
            float sz = v.z * SQRT_LOG2E_F, sw = v.w * SQRT_LOG2E_F;
            __half2 h01 = __floats2half2_rn(sx, sy);
            __half2 h23 = __floats2half2_rn(sz, sw);
            int ho = (k4 + 8 * (m & 7)) & 63;
            uint2 u; u.x = *(uint32*)&h01; u.y = *(uint32*)&h23;
            *(uint2*)&YsH[m * 64 + ho] = u;
            float p = sx * sx + sy * sy + sz * sz + sw * sw;
            p += __shfl_xor(p, 1);
            p += __shfl_xor(p, 2);
            p += __shfl_xor(p, 4);
            p += __shfl_xor(p, 8);
            if ((tid & 15) == 0) yy2[m] = p;
        }
    }
    // ---- init halo cols c_l 0..7 to 0 (finite filler for J=0) ----
    for (int idx = tid; idx < 8 * 140; idx += 512) P2h[idx] = 0;
    __syncthreads();

    const int l  = tid & 63;
    const int w  = tid >> 6;     // wave 0..7: rows [16w, 16w+16)
    const int lr = l & 15;
    const int lk = l >> 4;

    char* bbase = (char*)Dsk + (size_t)b * BSTRIDE;

    for (int J = 0; J < 4; ++J) {
        // ---- phase a: halo copy (prev chunk's last 7 cols -> c_l 1..7) ----
        if (J > 0) {
            for (int idx = tid; idx < 7 * 128; idx += 512) {
                int c = idx >> 7, row = idx & 127;
                P2h[(1 + c) * 140 + row] = P2h[(129 + c) * 140 + row];
            }
        }
        // ---- phase b: MFMA 128x128 (regs only) ----
        f32x4 acc[8];
#pragma unroll
        for (int ct = 0; ct < 8; ++ct) {
            f32x4 z = {0.f, 0.f, 0.f, 0.f};
            acc[ct] = z;
        }
#pragma unroll
        for (int ks = 0; ks < 2; ++ks) {
            f16x8 af, bf[8];
            {
                int row = 16 * w + lr;
                int ho = (ks * 32 + lk * 8 + 8 * (row & 7)) & 63;
                af = *(const f16x8*)&XsH[row * 64 + ho];
            }
#pragma unroll
            for (int ct = 0; ct < 8; ++ct) {
                int col = ct * 16 + lr;
                int ho = (ks * 32 + lk * 8 + 8 * (col & 7)) & 63;
                bf[ct] = *(const f16x8*)&YsH[col * 64 + ho];
            }
#pragma unroll
            for (int ct = 0; ct < 8; ++ct)
                acc[ct] = __builtin_amdgcn_mfma_f32_16x16x32_f16(
                    af, bf[ct], acc[ct], 0, 0, 0);
        }
        __syncthreads();   // halo copy complete; P2 main cols may be rewritten

        // ---- phase d: epilogue D = xx+yy-2S -> P2 c_l 8..135 ----
        {
            int rbase = 16 * w + 4 * lk;
            f32x4 xr = *(const f32x4*)&xx2[rbase];
#pragma unroll
            for (int ct = 0; ct < 8; ++ct) {
                int c = ct * 16 + lr;
                float yv = yy2[c];
                f32x4 a = acc[ct];
                float d0 = xr[0] + yv - 2.0f * a[0];
                float d1 = xr[1] + yv - 2.0f * a[1];
                float d2 = xr[2] + yv - 2.0f * a[2];
                float d3 = xr[3] + yv - 2.0f * a[3];
                __half2 h0 = __floats2half2_rn(d0, d1);
                __half2 h1 = __floats2half2_rn(d2, d3);
                uint2 u; u.x = *(uint32*)&h0; u.y = *(uint32*)&h1;
                *(uint2*)&P2h[(c + 8) * 140 + rbase] = u;
            }
        }
        __syncthreads();

        // ---- phase f: gather anti-diagonal slots -> global; stage next Y ----
        {
            const int Ll = tid & 15;
            const int Lg = 16 * strip + Ll;
            const int kb = (tid >> 4) * 4;
#pragma unroll
            for (int kk = 0; kk < 4; ++kk) {
                int k = kb + kk;
                uint32 h0 = P2h[(k + 8) * 140 + 8 * Ll + 0];
                uint32 h1 = P2h[(k + 7) * 140 + 8 * Ll + 1];
                uint32 h2 = P2h[(k + 6) * 140 + 8 * Ll + 2];
                uint32 h3 = P2h[(k + 5) * 140 + 8 * Ll + 3];
                uint32 h4 = P2h[(k + 4) * 140 + 8 * Ll + 4];
                uint32 h5 = P2h[(k + 3) * 140 + 8 * Ll + 5];
                uint32 h6 = P2h[(k + 2) * 140 + 8 * Ll + 6];
                uint32 h7 = P2h[(k + 1) * 140 + 8 * Ll + 7];
                uint4 wv;
                wv.x = h0 | (h1 << 16);
                wv.y = h2 | (h3 << 16);
                wv.z = h4 | (h5 << 16);
                wv.w = h6 | (h7 << 16);
                *(uint4*)(bbase + (size_t)(128 * J + 8 * Lg + 1 + k) * 1024
                          + Lg * 16) = wv;
            }
            // J=3 tail: slots u = 513..519 (partial rows, clamped filler)
            if (J == 3 && tid < 112) {
                int Lt = tid & 15, k = 128 + (tid >> 4);
                int Lgt = 16 * strip + Lt;
                uint32 hh[8];
#pragma unroll
                for (int r = 0; r < 8; ++r) {
                    int cl = k - r + 8; cl = (cl > 135) ? 135 : cl;
                    hh[r] = P2h[cl * 140 + 8 * Lt + r];
                }
                uint4 wv;
                wv.x = hh[0] | (hh[1] << 16);
                wv.y = hh[2] | (hh[3] << 16);
                wv.z = hh[4] | (hh[5] << 16);
                wv.w = hh[6] | (hh[7] << 16);
                *(uint4*)(bbase + (size_t)(384 + 8 * Lgt + 1 + k) * 1024
                          + Lgt * 16) = wv;
            }
            if (J < 3) {
                const float* Yg = Y + ((size_t)b * Mc + (J + 1) * 128) * DFc;
#pragma unroll
                for (int it = 0; it < 4; ++it) {
                    int e4 = it * 512 + tid;
                    int m = e4 >> 4, k4 = (e4 & 15) * 4;
                    float4 v = ((const float4*)Yg)[e4];
                    float sx = v.x * SQRT_LOG2E_F, sy = v.y * SQRT_LOG2E_F;
                    float sz = v.z * SQRT_LOG2E_F, sw = v.w * SQRT_LOG2E_F;
                    __half2 h01 = __floats2half2_rn(sx, sy);
                    __half2 h23 = __floats2half2_rn(sz, sw);
                    int ho = (k4 + 8 * (m & 7)) & 63;
                    uint2 u; u.x = *(uint32*)&h01; u.y = *(uint32*)&h23;
                    *(uint2*)&YsH[m * 64 + ho] = u;
                    float p = sx * sx + sy * sy + sz * sz + sw * sw;
                    p += __shfl_xor(p, 1);
                    p += __shfl_xor(p, 2);
                    p += __shfl_xor(p, 4);
                    p += __shfl_xor(p, 8);
                    if ((tid & 15) == 0) yy2[m] = p;
                }
            }
        }
        __syncthreads();
    }
}

// ---------------------------------------------------------------------------
// Kernel 2: anti-diagonal scan, 1 wave/batch, 8 rows/lane, all 8 cells per
// step mutually INDEPENDENT (true anti-diagonal i+j=s+1). No LDS, no
// barriers, no masking: free-running lanes stay ~1e10 (= BIG) via cvt
// saturation. Loop-carried chain per step = 1 softmin + 1 dpp, hidden under
// ~135 insts of independent issue.
// ---------------------------------------------------------------------------
#define ASTEP(S, Q)                                                        \
  {                                                                        \
    float up0 = dpp_shr1(BIGC, c7);                                        \
    uint4 dc = ring[Q];                                                    \
    {                                                                      \
      int sp = (S) + 4; sp = (sp > 1023) ? 1023 : sp;                      \
      ring[Q] = *(const uint4*)(tb + (size_t)sp * 1024 + voff);            \
    }                                                                      \
    float2 f01 = __half22float2(*(const __half2*)&dc.x);                   \
    float2 f23 = __half22float2(*(const __half2*)&dc.y);                   \
    float2 f45 = __half22float2(*(const __half2*)&dc.z);                   \
    float2 f67 = __half22float2(*(const __half2*)&dc.w);                   \
    float n0 = softmin3m(g0, up0, c0) + f01.x;                             \
    float n1 = softmin3m(g1, c0, c1) + f01.y;                              \
    float n2 = softmin3m(g2, c1, c2) + f23.x;                              \
    float n3 = softmin3m(g3, c2, c3) + f23.y;                              \
    float n4 = softmin3m(g4, c3, c4) + f45.x;                              \
    float n5 = softmin3m(g5, c4, c5) + f45.y;                              \
    float n6 = softmin3m(g6, c5, c6) + f67.x;                              \
    float n7 = softmin3m(g7, c6, c7) + f67.y;                              \
    if ((S) == scap) {                                                     \
      float vv = n0;                                                       \
      vv = (rcap == 1) ? n1 : vv;                                          \
      vv = (rcap == 2) ? n2 : vv;                                          \
      vv = (rcap == 3) ? n3 : vv;                                          \
      vv = (rcap == 4) ? n4 : vv;                                          \
      vv = (rcap == 5) ? n5 : vv;                                          \
      vv = (rcap == 6) ? n6 : vv;                                          \
      vv = (rcap == 7) ? n7 : vv;                                          \
      capv = (L == icap) ? vv : capv;                                      \
    }                                                                      \
    g0 = up0; g1 = c0; g2 = c1; g3 = c2;                                   \
    g4 = c3;  g5 = c4; g6 = c5; g7 = c6;                                   \
    c0 = n0; c1 = n1; c2 = n2; c3 = n3;                                    \
    c4 = n4; c5 = n5; c6 = n6; c7 = n7;                                    \
  }

__global__ __launch_bounds__(64) void scan_kernel(
    const uint32* __restrict__ Dsk,
    const int* __restrict__ X_len, const int* __restrict__ Y_len,
    float* __restrict__ out)
{
    const int L  = threadIdx.x;        // lane: DP rows 8L+1..8L+8
    const int bb = blockIdx.x;

    const int xl = X_len[bb], yl = Y_len[bb];
    const int icap = (xl - 1) >> 3;    // capture lane
    const int rcap = (xl - 1) & 7;     // capture row-in-lane
    const int scap = xl + yl - 1;      // capture step (anti-diag of (xl,yl))

    const char* tb = (const char*)Dsk + (size_t)bb * BSTRIDE;
    const int voff = L * 16;

    float c0 = BIGC, c1 = BIGC, c2 = BIGC, c3 = BIGC,
          c4 = BIGC, c5 = BIGC, c6 = BIGC, c7 = BIGC;
    float g1 = BIGC, g2 = BIGC, g3 = BIGC, g4 = BIGC,
          g5 = BIGC, g6 = BIGC, g7 = BIGC;
    float g0 = (L == 0) ? 0.0f : BIGC;     // R[0][0] seed
    float capv = 0.0f;

    uint4 ring[4];
#pragma unroll
    for (int j = 0; j < 4; ++j)
        ring[j] = *(const uint4*)(tb + (size_t)(1 + j) * 1024 + voff);

#pragma unroll 1
    for (int s0 = 1; s0 <= scap; s0 += 4) {
        ASTEP(s0 + 0, 0)
        ASTEP(s0 + 1, 1)
        ASTEP(s0 + 2, 2)
        ASTEP(s0 + 3, 3)
    }

    float o = rl(capv, icap);
    if (L == 0) out[bb] = o * LN2_F;
}

extern "C" void kernel_launch(void* const* d_in, const int* in_sizes, int n_in,
                              void* d_out, int out_size, void* d_ws, size_t ws_size,
                              hipStream_t stream)
{
    const float* X  = (const float*)d_in[0];
    const float* Y  = (const float*)d_in[1];
    const int*   xl = (const int*)d_in[2];
    const int*   yl = (const int*)d_in[3];
    float* out = (float*)d_out;
    uint32* Dsk = (uint32*)d_ws;   // 32 batches * 1 MB = 32 MB

    hipMemsetAsync(d_ws, 0, (size_t)Bc * BSTRIDE, stream);  // finite filler
    dist_kernel<<<dim3(4, Bc), 512, 0, stream>>>(X, Y, Dsk);
    scan_kernel<<<Bc, 64, 0, stream>>>(Dsk, xl, yl, out);
}

// Round 7
// 278.129 us; speedup vs baseline: 1.2070x; 1.2070x over previous
//
#include <hip/hip_runtime.h>
#include <hip/hip_fp16.h>
#include <cstddef>

#define Bc   32
#define Nc   512
#define Mc   512
#define DFc  64
#define BIGC 1.0e10f
#define LOG2E_F 1.4426950408889634f
#define LN2_F   0.6931471805599453f
#define SQRT_LOG2E_F 1.2011224087864498f

typedef unsigned int uint32;
typedef _Float16 f16x8 __attribute__((ext_vector_type(8)));
typedef float    f32x4 __attribute__((ext_vector_type(4)));

__device__ __forceinline__ float dpp_shr1(float oldv, float src) {
    return __int_as_float(__builtin_amdgcn_update_dpp(
        __float_as_int(oldv), __float_as_int(src), 0x138, 0xf, 0xf, false));
}
__device__ __forceinline__ float dpp_shr1_nc(float src) {
    return __int_as_float(__builtin_amdgcn_mov_dpp(
        __float_as_int(src), 0x138, 0xf, 0xf, false));
}
__device__ __forceinline__ float rl(float v, int lane) {
    return __int_as_float(__builtin_amdgcn_readlane(__float_as_int(v), lane));
}

// Bit-trick softmin, log2 domain, minus 127 (bias pre-folded into Dsk).
__device__ __forceinline__ float softmin3m(float a, float b, float c) {
    float mn = fminf(fminf(a, b), c);
    float mx = fmaxf(fmaxf(a, b), c);
    float md = __builtin_amdgcn_fmed3f(a, b, c);
    uint32 b1 = (uint32)fmaf(mn - mx, 8388608.0f, 1065353216.0f);
    uint32 b2 = (uint32)fmaf(mn - md, 8388608.0f, 1065353216.0f);
    float E = 1.0f + (__int_as_float(b1) + __int_as_float(b2));
    return fmaf((float)__float_as_uint(E), -1.1920929e-7f, mn);
}

// ---------------------------------------------------------------------------
// Kernel 1: MFMA distance computation (round-1/2 version, byte-identical).
// ---------------------------------------------------------------------------
__global__ __launch_bounds__(256) void dist_kernel(
    const float* __restrict__ X, const float* __restrict__ Y,
    uint32* __restrict__ Dsk)
{
    __shared__ __align__(16) unsigned char SMEM[35840];
    unsigned short* XsH = (unsigned short*)SMEM;            // 16384 B
    unsigned short* YsH = (unsigned short*)(SMEM + 16384);  // 16384 B
    uint32* P  = (uint32*)SMEM;                             // 34816 B (aliases Xs/Ys)
    float* xx2 = (float*)(SMEM + 34816);                    // 512 B (survives P)
    float* yy2 = (float*)(SMEM + 35328);                    // 512 B

    const int b     = blockIdx.z;
    const int strip = blockIdx.y;
    const int J     = blockIdx.x;
    const int tid   = threadIdx.x;

    const float* Xg = X + ((size_t)b * Nc + strip * 128) * DFc;
    const float* Yg = Y + ((size_t)b * Mc + J * 128) * DFc;

#pragma unroll
    for (int it = 0; it < 8; ++it) {
        int e4 = it * 256 + tid;
        int n = e4 >> 4, k4 = (e4 & 15) * 4;
        float4 v = ((const float4*)Xg)[e4];
        float sx = v.x * SQRT_LOG2E_F, sy = v.y * SQRT_LOG2E_F;
        float sz = v.z * SQRT_LOG2E_F, sw = v.w * SQRT_LOG2E_F;
        __half2 h01 = __floats2half2_rn(sx, sy);
        __half2 h23 = __floats2half2_rn(sz, sw);
        int ho = (k4 + 8 * (n & 7)) & 63;
        uint2 u; u.x = *(uint32*)&h01; u.y = *(uint32*)&h23;
        *(uint2*)&XsH[n * 64 + ho] = u;
        float p = sx * sx + sy * sy + sz * sz + sw * sw;
        p += __shfl_xor(p, 1);
        p += __shfl_xor(p, 2);
        p += __shfl_xor(p, 4);
        p += __shfl_xor(p, 8);
        if ((tid & 15) == 0) xx2[n] = p + 127.0f;   // fold the +127 bias here
    }
#pragma unroll
    for (int it = 0; it < 8; ++it) {
        int e4 = it * 256 + tid;
        int m = e4 >> 4, k4 = (e4 & 15) * 4;
        float4 v = ((const float4*)Yg)[e4];
        float sx = v.x * SQRT_LOG2E_F, sy = v.y * SQRT_LOG2E_F;
        float sz = v.z * SQRT_LOG2E_F, sw = v.w * SQRT_LOG2E_F;
        __half2 h01 = __floats2half2_rn(sx, sy);
        __half2 h23 = __floats2half2_rn(sz, sw);
        int ho = (k4 + 8 * (m & 7)) & 63;
        uint2 u; u.x = *(uint32*)&h01; u.y = *(uint32*)&h23;
        *(uint2*)&YsH[m * 64 + ho] = u;
        float p = sx * sx + sy * sy + sz * sz + sw * sw;
        p += __shfl_xor(p, 1);
        p += __shfl_xor(p, 2);
        p += __shfl_xor(p, 4);
        p += __shfl_xor(p, 8);
        if ((tid & 15) == 0) yy2[m] = p;
    }
    __syncthreads();

    const int l  = tid & 63;
    const int w  = tid >> 6;     // wave 0..3: rows [32w, 32w+32)
    const int lr = l & 15;       // fragment row/col
    const int lk = l >> 4;       // fragment k-group

    f32x4 acc[2][8];
#pragma unroll
    for (int rt = 0; rt < 2; ++rt)
#pragma unroll
        for (int ct = 0; ct < 8; ++ct) {
            f32x4 z = {0.f, 0.f, 0.f, 0.f};
            acc[rt][ct] = z;
        }

#pragma unroll
    for (int ks = 0; ks < 2; ++ks) {
        f16x8 af[2], bf[8];
#pragma unroll
        for (int rt = 0; rt < 2; ++rt) {
            int row = w * 32 + rt * 16 + lr;
            int ho = (ks * 32 + lk * 8 + 8 * (row & 7)) & 63;
            af[rt] = *(const f16x8*)&XsH[row * 64 + ho];
        }
#pragma unroll
        for (int ct = 0; ct < 8; ++ct) {
            int col = ct * 16 + lr;
            int ho = (ks * 32 + lk * 8 + 8 * (col & 7)) & 63;
            bf[ct] = *(const f16x8*)&YsH[col * 64 + ho];
        }
#pragma unroll
        for (int rt = 0; rt < 2; ++rt)
#pragma unroll
            for (int ct = 0; ct < 8; ++ct)
                acc[rt][ct] = __builtin_amdgcn_mfma_f32_16x16x32_f16(
                    af[rt], bf[ct], acc[rt][ct], 0, 0, 0);
    }
    __syncthreads();   // Xs/Ys dead; P may now overwrite them

#pragma unroll
    for (int rt = 0; rt < 2; ++rt) {
        int rbase = w * 32 + rt * 16 + 4 * lk;
        f32x4 xr = *(const f32x4*)&xx2[rbase];
        int p0 = rbase >> 1;
#pragma unroll
        for (int ct = 0; ct < 8; ++ct) {
            int c = ct * 16 + lr;
            float yv = yy2[c];
            f32x4 a = acc[rt][ct];
            float d0 = xr[0] + yv - 2.0f * a[0];
            float d1 = xr[1] + yv - 2.0f * a[1];
            float d2 = xr[2] + yv - 2.0f * a[2];
            float d3 = xr[3] + yv - 2.0f * a[3];
            __half2 h0 = __floats2half2_rn(d0, d1);
            __half2 h1 = __floats2half2_rn(d2, d3);
            P[c * 67 + p0]     = *(uint32*)&h0;
            P[c * 67 + p0 + 1] = *(uint32*)&h1;
        }
    }
    __syncthreads();

    const int q = tid >> 6;
    uint4* outt = (uint4*)Dsk + (((size_t)b * 4 + strip) * 4 + J) * 4096;
    const uint32* Pl = P + l;
#pragma unroll
    for (int gi = 0; gi < 16; ++gi) {
        int g = q + 4 * gi;
        int ka = 4 * g - 2 * l;
        int c0 = min(max(ka,     0), 127);
        int c1 = min(max(ka + 1, 0), 127);
        int c2 = min(max(ka + 2, 0), 127);
        int c3 = min(max(ka + 3, 0), 127);
        uint32 p0 = Pl[c0 * 67];
        uint32 p1 = Pl[c1 * 67];
        uint32 p2 = Pl[c2 * 67];
        uint32 p3 = Pl[c3 * 67];
        uint4 v;
        v.x = (p0 & 0xffffu) | (p1 << 16);
        v.y = (p0 >> 16)     | (p1 & 0xffff0000u);
        v.z = (p2 & 0xffffu) | (p3 << 16);
        v.w = (p2 >> 16)     | (p3 & 0xffff0000u);
        outt[g * 64 + l] = v;
    }
}

// ---------------------------------------------------------------------------
// Kernel 2: round-2 superstep scan, TWO BATCHES PER BLOCK (8 waves, 512 thr).
// Waves 0-3 = batch bb, waves 4-7 = batch bb+16 -> waves wl and wl+4 share a
// SIMD, so each wave's dependency-stall cycles are filled by the other
// batch's independent issue. SSTEP math, prefetch ring, Dsk layout all
// byte-identical to round 2. Loop bound = pair-max supersteps (guards keep
// barrier counts uniform; out-of-range supersteps are no-ops).
// ---------------------------------------------------------------------------
#define SSTEP(T, dAw, dBw, PH1)                                            \
  {                                                                        \
    float2 fA = __half22float2(*(const __half2*)&(dAw));                   \
    float2 fB = __half22float2(*(const __half2*)&(dBw));                   \
    float u1, u2;                                                          \
    if (PH1) {                                                             \
      u1 = dpp_shr1(rl(Fodd, (T) - 1), pub1);                              \
      u2 = dpp_shr1(rl(Fev,  (T) - 1), curB);                              \
    } else {                                                               \
      u1 = dpp_shr1_nc(pub1);                                              \
      u2 = dpp_shr1_nc(curB);                                              \
    }                                                                      \
    float A1 = softmin3m(diagA, u1, curA) + fA.x;                          \
    float A2 = softmin3m(u1, u2, A1) + fA.y;                               \
    float B1 = softmin3m(curA, A1, curB) + fB.x;                           \
    float B2 = softmin3m(A1, A2, B1) + fB.y;                               \
    if ((T) == scap)                                                       \
      capv = useB ? (useC2 ? B2 : B1) : (useC2 ? A2 : A1);                 \
    bool act = (PH1) ? (l < (T)) : (l >= (T) - 64);                        \
    pub1  = act ? B1 : curB;   /* reads curB BEFORE update */              \
    curA  = act ? A2 : curA;                                               \
    curB  = act ? B2 : curB;                                               \
    diagA = u2;                                                            \
    if (!(PH1)) { wbase[2 * (T) - 127] = B1; wbase[2 * (T) - 126] = B2; }  \
  }

__global__ __launch_bounds__(512) void scan_kernel(
    const uint32* __restrict__ Dsk,
    const int* __restrict__ X_len, const int* __restrict__ Y_len,
    float* __restrict__ out)
{
    __shared__ __align__(16) float Frow[8][520];
    __shared__ float dumpArr[136];

    const int tid = threadIdx.x;
    const int l   = tid & 63;
    const int w8  = __builtin_amdgcn_readfirstlane(tid >> 6);  // 0..7
    const int half = w8 >> 2;                 // batch-half of this wave
    const int wl   = w8 & 3;                  // strip 0..3
    const int bb   = blockIdx.x + 16 * half;

    const int xlA = X_len[blockIdx.x],      ylA = Y_len[blockIdx.x];
    const int xlB = X_len[blockIdx.x + 16], ylB = Y_len[blockIdx.x + 16];
    const int xl = half ? xlB : xlA;
    const int yl = half ? ylB : ylA;
    const int kA = ((xlA - 1) >> 7) + ((ylA - 1) >> 7);
    const int kB = ((xlB - 1) >> 7) + ((ylB - 1) >> 7);
    const int kloop = (kA > kB) ? kA : kB;    // block-uniform superstep count

    const int wxl  = (xl - 1) >> 7;           // capture strip
    const int iw   = (xl - 1) & 127;
    const int lcap = iw >> 1;                 // capture lane
    const int useB = iw & 1;                  // row parity (A/B)
    const int Jcap = (yl - 1) >> 7;           // capture tile (128-col)
    const int ycol = yl - (Jcap << 7);        // 1..128
    const int useC2 = 1 - (ycol & 1);         // even rel-col -> second cell
    const int tcap = ((ycol + 1) >> 1) + lcap;   // in [1,127]

    const bool is63 = (l == 63);
    const int voff = l * 16;

    // wave-uniform byte base for this strip's tiles (J advances by 65536 B)
    const char* tbw = (const char*)Dsk +
        ((((size_t)bb * 4 + wl) * 4) * 4096) * 16;

    if (l == 0) Frow[w8][0] = BIGC;           // col-0 border for f0 at J=0
    __syncthreads();

    float curA = BIGC, curB = BIGC, pub1 = BIGC;
    float diagA = BIGC;
    float capv = 0.0f;

    // prologue prefetch for tile J=0 (only waves that will ever be active)
    uint4 dreg[8];
    if (wl <= wxl) {
#pragma unroll
        for (int q = 0; q < 8; ++q)
            dreg[q] = *(const uint4*)(tbw + voff + q * 1024);
    }

    for (int k = 0; k <= kloop; ++k) {
        int J = k - wl;
        if (wl <= wxl && 0 <= J && J <= Jcap) {
            const int j0 = J << 7;
            float Fodd, Fev, f0;
            if (wl > 0) {
                Fodd = Frow[w8 - 1][j0 + 1 + 2 * l];   // odd rel-cols 1..127
                Fev  = Frow[w8 - 1][j0 + 2 + 2 * l];   // even rel-cols 2..128
                f0   = Frow[w8 - 1][j0];               // diag seed col j0
            } else {
                Fodd = BIGC; Fev = BIGC;
                f0 = (J == 0) ? 0.0f : BIGC;           // R[0][0] = 0
            }
            diagA = (l == 0) ? f0 : diagA;

            const char* tb = tbw + (size_t)J * 65536;
            const int scap = (wl == wxl && J == Jcap) ? tcap : -1000;
            float* wbase = is63 ? (&Frow[w8][j0]) : (dumpArr + 4);
            const bool nextJ = (J < Jcap);

            // ---- phase 1: g 0..31 (t = 1..64): lane0 inject, no stores ----
#pragma unroll 1
            for (int m = 0; m < 4; ++m) {
#pragma unroll
                for (int q = 0; q < 8; ++q) {
                    const int g = m * 8 + q;
                    uint4 dc = dreg[q];
                    SSTEP(2 * g + 1, dc.x, dc.y, true)
                    SSTEP(2 * g + 2, dc.z, dc.w, true)
                    dreg[q] = *(const uint4*)(tb + voff + (g + 8) * 1024);
                }
            }
            // t=64 boundary publish: lane63 (just activated) cols 1,2
            wbase[1] = pub1;
            wbase[2] = curB;

            // ---- phase 2: g 32..55 (t = 65..112): no inject, store pair ----
#pragma unroll 1
            for (int m = 4; m < 7; ++m) {
#pragma unroll
                for (int q = 0; q < 8; ++q) {
                    const int g = m * 8 + q;
                    uint4 dc = dreg[q];
                    SSTEP(2 * g + 1, dc.x, dc.y, false)
                    SSTEP(2 * g + 2, dc.z, dc.w, false)
                    dreg[q] = *(const uint4*)(tb + voff + (g + 8) * 1024);
                }
            }
            // ---- peel: g 56..63 (t = 113..127; t=128 skipped).
            //      Interleave prologue prefetch for tile J+1. ----
#pragma unroll
            for (int q = 0; q < 8; ++q) {
                const int g = 56 + q;
                uint4 dc = dreg[q];
                SSTEP(2 * g + 1, dc.x, dc.y, false)
                if (g < 63) { SSTEP(2 * g + 2, dc.z, dc.w, false) }
                if (nextJ)
                    dreg[q] = *(const uint4*)(tb + 65536 + voff + q * 1024);
            }
        }
        __syncthreads();
    }

    if (wl == wxl) {
        float o = rl(capv, lcap);
        if (l == 0) out[bb] = o * LN2_F;
    }
}

extern "C" void kernel_launch(void* const* d_in, const int* in_sizes, int n_in,
                              void* d_out, int out_size, void* d_ws, size_t ws_size,
                              hipStream_t stream)
{
    const float* X  = (const float*)d_in[0];
    const float* Y  = (const float*)d_in[1];
    const int*   xl = (const int*)d_in[2];
    const int*   yl = (const int*)d_in[3];
    float* out = (float*)d_out;
    uint32* Dsk = (uint32*)d_ws;   // 32 b * 4 strips * 4 J * 64 KB = 32 MB

    dist_kernel<<<dim3(4, 4, Bc), 256, 0, stream>>>(X, Y, Dsk);
    scan_kernel<<<16, 512, 0, stream>>>(Dsk, xl, yl, out);
}

// Round 9
// 168.565 us; speedup vs baseline: 1.9916x; 1.6500x over previous
//
#include <hip/hip_runtime.h>
#include <hip/hip_fp16.h>
#include <cstddef>

#define Bc   32
#define Nc   512
#define Mc   512
#define DFc  64
#define BIGC 1.0e10f
#define LOG2E_F 1.4426950408889634f
#define LN2_F   0.6931471805599453f
#define SQRT_LOG2E_F 1.2011224087864498f

typedef unsigned int uint32;
typedef _Float16 f16x8 __attribute__((ext_vector_type(8)));
typedef float    f32x4 __attribute__((ext_vector_type(4)));

__device__ __forceinline__ float dpp_shr1(float oldv, float src) {
    return __int_as_float(__builtin_amdgcn_update_dpp(
        __float_as_int(oldv), __float_as_int(src), 0x138, 0xf, 0xf, false));
}
__device__ __forceinline__ float rl(float v, int lane) {
    return __int_as_float(__builtin_amdgcn_readlane(__float_as_int(v), lane));
}

// Bit-trick softmin, log2 domain, minus 127 (bias pre-folded into Dsk).
__device__ __forceinline__ float softmin3m(float a, float b, float c) {
    float mn = fminf(fminf(a, b), c);
    float mx = fmaxf(fmaxf(a, b), c);
    float md = __builtin_amdgcn_fmed3f(a, b, c);
    uint32 b1 = (uint32)fmaf(mn - mx, 8388608.0f, 1065353216.0f);
    uint32 b2 = (uint32)fmaf(mn - md, 8388608.0f, 1065353216.0f);
    float E = 1.0f + (__int_as_float(b1) + __int_as_float(b2));
    return fmaf((float)__float_as_uint(E), -1.1920929e-7f, mn);
}

// ---------------------------------------------------------------------------
// Kernel 1: MFMA distance computation. Staging/MFMA/epilogue = round 2.
// NEW output stage: GLOBAL-LINEAR skewed layout. Per (b,strip) region of
// 256 KB at Dsk + (b*4+strip)*262144: entry (p,l) 16B at p*1024 + l*16 holds
//   h0 = {dA,dB} for col-pair c = 2p - l,  h1 = {dA,dB} for c+1,
// dA = half2(D[2l][2c],D[2l][2c+1]), dB = rows 2l+1 (strip-local, 0-based).
// Tile J owns c in [64J,64J+64): even lanes 32 full entries; odd lanes 31
// full + two 8B straddle halves (adjacent tiles write disjoint halves of the
// shared boundary entry). Unwritten filler only feeds act-masked lanes.
// ---------------------------------------------------------------------------
__global__ __launch_bounds__(256) void dist_kernel(
    const float* __restrict__ X, const float* __restrict__ Y,
    uint32* __restrict__ Dsk)
{
    __shared__ __align__(16) unsigned char SMEM[35840];
    unsigned short* XsH = (unsigned short*)SMEM;            // 16384 B
    unsigned short* YsH = (unsigned short*)(SMEM + 16384);  // 16384 B
    uint32* P  = (uint32*)SMEM;                             // 34816 B (aliases Xs/Ys)
    float* xx2 = (float*)(SMEM + 34816);                    // 512 B (survives P)
    float* yy2 = (float*)(SMEM + 35328);                    // 512 B

    const int b     = blockIdx.z;
    const int strip = blockIdx.y;
    const int J     = blockIdx.x;
    const int tid   = threadIdx.x;

    const float* Xg = X + ((size_t)b * Nc + strip * 128) * DFc;
    const float* Yg = Y + ((size_t)b * Mc + J * 128) * DFc;

#pragma unroll
    for (int it = 0; it < 8; ++it) {
        int e4 = it * 256 + tid;
        int n = e4 >> 4, k4 = (e4 & 15) * 4;
        float4 v = ((const float4*)Xg)[e4];
        float sx = v.x * SQRT_LOG2E_F, sy = v.y * SQRT_LOG2E_F;
        float sz = v.z * SQRT_LOG2E_F, sw = v.w * SQRT_LOG2E_F;
        __half2 h01 = __floats2half2_rn(sx, sy);
        __half2 h23 = __floats2half2_rn(sz, sw);
        int ho = (k4 + 8 * (n & 7)) & 63;
        uint2 u; u.x = *(uint32*)&h01; u.y = *(uint32*)&h23;
        *(uint2*)&XsH[n * 64 + ho] = u;
        float p = sx * sx + sy * sy + sz * sz + sw * sw;
        p += __shfl_xor(p, 1);
        p += __shfl_xor(p, 2);
        p += __shfl_xor(p, 4);
        p += __shfl_xor(p, 8);
        if ((tid & 15) == 0) xx2[n] = p + 127.0f;   // fold the +127 bias here
    }
#pragma unroll
    for (int it = 0; it < 8; ++it) {
        int e4 = it * 256 + tid;
        int m = e4 >> 4, k4 = (e4 & 15) * 4;
        float4 v = ((const float4*)Yg)[e4];
        float sx = v.x * SQRT_LOG2E_F, sy = v.y * SQRT_LOG2E_F;
        float sz = v.z * SQRT_LOG2E_F, sw = v.w * SQRT_LOG2E_F;
        __half2 h01 = __floats2half2_rn(sx, sy);
        __half2 h23 = __floats2half2_rn(sz, sw);
        int ho = (k4 + 8 * (m & 7)) & 63;
        uint2 u; u.x = *(uint32*)&h01; u.y = *(uint32*)&h23;
        *(uint2*)&YsH[m * 64 + ho] = u;
        float p = sx * sx + sy * sy + sz * sz + sw * sw;
        p += __shfl_xor(p, 1);
        p += __shfl_xor(p, 2);
        p += __shfl_xor(p, 4);
        p += __shfl_xor(p, 8);
        if ((tid & 15) == 0) yy2[m] = p;
    }
    __syncthreads();

    const int l  = tid & 63;
    const int w  = tid >> 6;     // wave 0..3: rows [32w, 32w+32)
    const int lr = l & 15;       // fragment row/col
    const int lk = l >> 4;       // fragment k-group

    f32x4 acc[2][8];
#pragma unroll
    for (int rt = 0; rt < 2; ++rt)
#pragma unroll
        for (int ct = 0; ct < 8; ++ct) {
            f32x4 z = {0.f, 0.f, 0.f, 0.f};
            acc[rt][ct] = z;
        }

#pragma unroll
    for (int ks = 0; ks < 2; ++ks) {
        f16x8 af[2], bf[8];
#pragma unroll
        for (int rt = 0; rt < 2; ++rt) {
            int row = w * 32 + rt * 16 + lr;
            int ho = (ks * 32 + lk * 8 + 8 * (row & 7)) & 63;
            af[rt] = *(const f16x8*)&XsH[row * 64 + ho];
        }
#pragma unroll
        for (int ct = 0; ct < 8; ++ct) {
            int col = ct * 16 + lr;
            int ho = (ks * 32 + lk * 8 + 8 * (col & 7)) & 63;
            bf[ct] = *(const f16x8*)&YsH[col * 64 + ho];
        }
#pragma unroll
        for (int rt = 0; rt < 2; ++rt)
#pragma unroll
            for (int ct = 0; ct < 8; ++ct)
                acc[rt][ct] = __builtin_amdgcn_mfma_f32_16x16x32_f16(
                    af[rt], bf[ct], acc[rt][ct], 0, 0, 0);
    }
    __syncthreads();   // Xs/Ys dead; P may now overwrite them

#pragma unroll
    for (int rt = 0; rt < 2; ++rt) {
        int rbase = w * 32 + rt * 16 + 4 * lk;
        f32x4 xr = *(const f32x4*)&xx2[rbase];
        int p0 = rbase >> 1;
#pragma unroll
        for (int ct = 0; ct < 8; ++ct) {
            int c = ct * 16 + lr;
            float yv = yy2[c];
            f32x4 a = acc[rt][ct];
            float d0 = xr[0] + yv - 2.0f * a[0];
            float d1 = xr[1] + yv - 2.0f * a[1];
            float d2 = xr[2] + yv - 2.0f * a[2];
            float d3 = xr[3] + yv - 2.0f * a[3];
            __half2 h0 = __floats2half2_rn(d0, d1);
            __half2 h1 = __floats2half2_rn(d2, d3);
            P[c * 67 + p0]     = *(uint32*)&h0;
            P[c * 67 + p0 + 1] = *(uint32*)&h1;
        }
    }
    __syncthreads();

    // ---- output stage: global-linear skewed slot layout ----
    {
        char* rbp = (char*)Dsk + (size_t)((b * 4 + strip) * 262144);
        const int q = tid >> 6;              // 0..3
        const int lpar = l & 1;
        const int nfull = 32 - lpar;         // 32 even-l, 31 odd-l
        const int pbase = 32 * J + ((l + lpar) >> 1);
        for (int k = q; k < nfull; k += 4) {
            int p = pbase + k;
            int tc0 = 4 * k + 2 * lpar;      // local col 2(c-64J), c = 2p-l
            uint32 p0 = P[(tc0    ) * 67 + l];
            uint32 p1 = P[(tc0 + 1) * 67 + l];
            uint32 p2 = P[(tc0 + 2) * 67 + l];
            uint32 p3 = P[(tc0 + 3) * 67 + l];
            uint4 v;
            v.x = (p0 & 0xffffu) | (p1 << 16);
            v.y = (p0 >> 16)     | (p1 & 0xffff0000u);
            v.z = (p2 & 0xffffu) | (p3 << 16);
            v.w = (p2 >> 16)     | (p3 & 0xffff0000u);
            *(uint4*)(rbp + p * 1024 + l * 16) = v;
        }
        if (lpar && q == 3) {
            // left straddle: c = 64J (h=1 of entry pL), local cols 0,1
            int pL = 32 * J + ((l - 1) >> 1);
            uint32 a0 = P[0 * 67 + l], a1 = P[1 * 67 + l];
            uint2 u;
            u.x = (a0 & 0xffffu) | (a1 << 16);
            u.y = (a0 >> 16)     | (a1 & 0xffff0000u);
            *(uint2*)(rbp + pL * 1024 + l * 16 + 8) = u;
            // right straddle: c = 64J+63 (h=0 of entry pR), local cols 126,127
            int pR = 32 * J + 31 + ((l + 1) >> 1);
            uint32 b0 = P[126 * 67 + l], b1 = P[127 * 67 + l];
            uint2 w2;
            w2.x = (b0 & 0xffffu) | (b1 << 16);
            w2.y = (b0 >> 16)     | (b1 & 0xffff0000u);
            *(uint2*)(rbp + pR * 1024 + l * 16) = w2;
        }
    }
}

// ---------------------------------------------------------------------------
// Kernel 2: CONTINUOUS-SWEEP scan (unchanged from round 8). Each wave sweeps
// its 128-row strip across all 512 cols (col-pair c = slot - lane); lane skew
// paid once (slots 889 -> ~520 avg). Strip edges stream through a 64-entry
// LDS ring: lane 63 publishes (B1,B2) each slot; next wave (delay 80 slots)
// consumes them as dpp old-values. Write->read gap = 17 slots, barrier every
// 16 -> visibility guaranteed; overwrite 47 slots after read. SSTEP math
// identical to r2 (bit-identical active-cell results).
// ---------------------------------------------------------------------------
#define NSTEP(J_, dAw, dBw)                                                \
  {                                                                        \
    float u1 = dpp_shr1(evO[J_], pub1);                                    \
    float u2 = dpp_shr1(evE[J_], curB);                                    \
    float2 fA = __half22float2(*(const __half2*)&(dAw));                   \
    float2 fB = __half22float2(*(const __half2*)&(dBw));                   \
    float A1 = softmin3m(diagA, u1, curA) + fA.x;                          \
    float A2 = softmin3m(u1, u2, A1) + fA.y;                               \
    float B1 = softmin3m(curA, A1, curB) + fB.x;                           \
    float B2 = softmin3m(A1, A2, B1) + fB.y;                               \
    if (ls0 + (J_) == scap)                                                \
      capv = useB ? (useC2 ? B2 : B1) : (useC2 ? A2 : A1);                 \
    {                                                                      \
      int c = ls0 + (J_) - l;                                              \
      bool act = ((unsigned)c <= 255u);                                    \
      pub1  = act ? B1 : curB;   /* reads curB BEFORE update */            \
      curA  = act ? A2 : curA;                                             \
      curB  = act ? B2 : curB;                                             \
    }                                                                      \
    diagA = u2;                                                            \
    {                                                                      \
      float* wbs = pubEdge ? &ering[wl][(ls0 + (J_) + 1) & 63][0] : dumpw; \
      wbs[0] = B1; wbs[1] = B2;                                            \
    }                                                                      \
  }

__global__ __launch_bounds__(256) void scan_kernel(
    const uint32* __restrict__ Dsk,
    const int* __restrict__ X_len, const int* __restrict__ Y_len,
    float* __restrict__ out)
{
    __shared__ __align__(16) float ering[4][64][2];   // strip-edge rings
    __shared__ float dumpw[4];

    const int tid = threadIdx.x;
    const int l   = tid & 63;
    const int wl  = __builtin_amdgcn_readfirstlane(tid >> 6);  // strip 0..3
    const int bb  = blockIdx.x;

    const int xl = X_len[bb], yl = Y_len[bb];
    const int gcap = (xl - 1) >> 1;          // global row-pair of capture
    const int wcap = gcap >> 6;              // capture wave
    const int lcap = gcap & 63;              // capture lane
    const int useB  = (xl - 1) & 1;          // even xl -> B row
    const int useC2 = (yl - 1) & 1;          // even yl -> second col of pair
    const int ccap  = (yl - 1) >> 1;         // capture col-pair
    const int scapw = ccap + lcap;           // capture local slot (<= 318)
    const int scap  = (wl == wcap) ? scapw : -1000;
    const int blkmax = (80 * wcap + scapw) >> 4;

    const char* tbw = (const char*)Dsk + (size_t)((bb * 4 + wl) * 262144);
    const int voff = l * 16;
    const bool pubEdge = (l == 63) && (wl < 3);

    float curA = BIGC, curB = BIGC, pub1 = BIGC;
    float diagA = (wl == 0 && l == 0) ? 0.0f : BIGC;   // R[0][0] seed
    float capv = 0.0f;

    // Dsk prefetch ring: 8 uint4 = 16 slots ahead, linear addressing.
    uint4 dreg[8];
#pragma unroll
    for (int q = 0; q < 8; ++q)
        dreg[q] = *(const uint4*)(tbw + q * 1024 + voff);

    for (int blk = 0; blk <= blkmax; ++blk) {
        const int ls0 = blk * 16 - 80 * wl;
        if (wl <= wcap && 0 <= ls0 && ls0 <= 304) {
            // edge pairs for cols ls0..ls0+15 (all written >=1 barrier ago)
            float evO[16], evE[16];
            if (wl > 0) {
                const float* rb = &ering[wl - 1][ls0 & 63][0];
#pragma unroll
                for (int j = 0; j < 16; j += 2) {
                    float4 t = *(const float4*)(rb + 2 * j);
                    bool v0 = (ls0 + j)     <= 255;
                    bool v1 = (ls0 + j + 1) <= 255;
                    evO[j]     = v0 ? t.x : BIGC;
                    evE[j]     = v0 ? t.y : BIGC;
                    evO[j + 1] = v1 ? t.z : BIGC;
                    evE[j + 1] = v1 ? t.w : BIGC;
                }
            } else {
#pragma unroll
                for (int j = 0; j < 16; ++j) { evO[j] = BIGC; evE[j] = BIGC; }
            }
            const char* tbB = tbw + (size_t)(ls0 >> 1) * 1024 + voff;
#pragma unroll
            for (int q = 0; q < 8; ++q) {
                uint4 dc = dreg[q];
                dreg[q] = *(const uint4*)(tbB + (q + 8) * 1024);
                NSTEP(2 * q,     dc.x, dc.y)
                NSTEP(2 * q + 1, dc.z, dc.w)
            }
        }
        __syncthreads();
    }

    if (wl == wcap) {
        float o = rl(capv, lcap);
        if (l == 0) out[bb] = o * LN2_F;
    }
}

extern "C" void kernel_launch(void* const* d_in, const int* in_sizes, int n_in,
                              void* d_out, int out_size, void* d_ws, size_t ws_size,
                              hipStream_t stream)
{
    const float* X  = (const float*)d_in[0];
    const float* Y  = (const float*)d_in[1];
    const int*   xl = (const int*)d_in[2];
    const int*   yl = (const int*)d_in[3];
    float* out = (float*)d_out;
    uint32* Dsk = (uint32*)d_ws;   // 32 b * 4 strips * 256 KB = 32 MB

    dist_kernel<<<dim3(4, 4, Bc), 256, 0, stream>>>(X, Y, Dsk);
    scan_kernel<<<Bc, 256, 0, stream>>>(Dsk, xl, yl, out);
}